// Round 3
// baseline (701.324 us; speedup 1.0000x reference)
//
#include <hip/hip_runtime.h>
#include <math.h>

#define NEXP 8
#define TILE 128
#define BK 32

typedef __attribute__((ext_vector_type(8))) short short8;
typedef __attribute__((ext_vector_type(4))) float float4v;

__device__ __forceinline__ unsigned short f2bf(float f) {
  union { float f; unsigned u; } v; v.f = f;
  unsigned r = v.u + 0x7FFFu + ((v.u >> 16) & 1u);  // RNE
  return (unsigned short)(r >> 16);
}
__device__ __forceinline__ unsigned pack2(float a, float b) {
  return (unsigned)f2bf(a) | ((unsigned)f2bf(b) << 16);
}

// async global->LDS, 16B per lane. LDS dst is wave-uniform base + lane*16.
__device__ __forceinline__ void gll16(const void* g, void* l) {
  __builtin_amdgcn_global_load_lds(
      (const __attribute__((address_space(1))) unsigned int*)(unsigned long long)(uintptr_t)g,
      (__attribute__((address_space(3))) unsigned int*)(unsigned)(uintptr_t)l,
      16, 0, 0);
}

// ---------------- standalone pack (used for down weights) ----------------
// dst panels [128 rows][32 cols] bf16, FRAGMENT-MAJOR:
// [rowchunk r>>4][colgrp c>>3][row r&15][8 cols]  (conflict-free ds_read_b128)
__global__ __launch_bounds__(256) void pack_w_kernel(
    const float* __restrict__ src, unsigned short* __restrict__ dst, int K) {
  const int ks = blockIdx.x, rt = blockIdx.y, e = blockIdx.z;
  const int n_ks = gridDim.x, n_rt = gridDim.y;
  const int r = threadIdx.x >> 1, half = threadIdx.x & 1;
  const size_t R = (size_t)n_rt * TILE;
  const float4* s = (const float4*)(src + ((size_t)e * R + rt * TILE + r) * K + ks * BK + half * 16);
  float4 v0 = s[0], v1 = s[1], v2 = s[2], v3 = s[3];
  uint4 o0, o1;
  o0.x = pack2(v0.x, v0.y); o0.y = pack2(v0.z, v0.w);
  o0.z = pack2(v1.x, v1.y); o0.w = pack2(v1.z, v1.w);
  o1.x = pack2(v2.x, v2.y); o1.y = pack2(v2.z, v2.w);
  o1.z = pack2(v3.x, v3.y); o1.w = pack2(v3.z, v3.w);
  unsigned short* pb = dst + ((size_t)(e * n_rt + rt) * n_ks + ks) * (TILE * BK)
                           + (r >> 4) * 512 + (r & 15) * 8;
  *(uint4*)(pb + (2 * half) * 128)     = o0;
  *(uint4*)(pb + (2 * half + 1) * 128) = o1;
}

// ---------------- fused prep: gw/uw pack + x->bf16 + routing (one launch) ----------------
__global__ __launch_bounds__(256) void prep_kernel(
    const float* __restrict__ gw, const float* __restrict__ uw,
    const float* __restrict__ x, const float* __restrict__ cw,
    const float* __restrict__ cb, const float* __restrict__ wealth,
    unsigned short* __restrict__ gwp, unsigned short* __restrict__ uwp,
    unsigned short* __restrict__ xb, int* __restrict__ plist,
    int* __restrict__ counts, float* __restrict__ w_rt,
    int T, int H, int n4, int z_conv, int z_rout) {
  const int z = blockIdx.z;
  if (z < z_conv) {
    // ---- weight pack: z<NEXP -> gw, else uw ----
    const int e = (z < NEXP) ? z : z - NEXP;
    const float* src = (z < NEXP) ? gw : uw;
    unsigned short* dst = (z < NEXP) ? gwp : uwp;
    const int ks = blockIdx.x, rt = blockIdx.y;
    const int n_ks = gridDim.x, n_rt = gridDim.y;
    const int r = threadIdx.x >> 1, half = threadIdx.x & 1;
    const int K = H;
    const size_t R = (size_t)n_rt * TILE;
    const float4* s = (const float4*)(src + ((size_t)e * R + rt * TILE + r) * K + ks * BK + half * 16);
    float4 v0 = s[0], v1 = s[1], v2 = s[2], v3 = s[3];
    uint4 o0, o1;
    o0.x = pack2(v0.x, v0.y); o0.y = pack2(v0.z, v0.w);
    o0.z = pack2(v1.x, v1.y); o0.w = pack2(v1.z, v1.w);
    o1.x = pack2(v2.x, v2.y); o1.y = pack2(v2.z, v2.w);
    o1.z = pack2(v3.x, v3.y); o1.w = pack2(v3.z, v3.w);
    unsigned short* pb = dst + ((size_t)(e * n_rt + rt) * n_ks + ks) * (TILE * BK)
                             + (r >> 4) * 512 + (r & 15) * 8;
    *(uint4*)(pb + (2 * half) * 128)     = o0;
    *(uint4*)(pb + (2 * half + 1) * 128) = o1;
  } else if (z < z_rout) {
    // ---- x -> bf16 ----
    int bl = blockIdx.y * gridDim.x + blockIdx.x;
    int i = ((z - z_conv) * gridDim.x * gridDim.y + bl) * 256 + threadIdx.x;
    if (i < n4) {
      float4 v = ((const float4*)x)[i];
      uint2 o; o.x = pack2(v.x, v.y); o.y = pack2(v.z, v.w);
      ((uint2*)xb)[i] = o;
    }
  } else {
    // ---- routing: one wave per token ----
    int bl = blockIdx.y * gridDim.x + blockIdx.x;
    int t = ((z - z_rout) * gridDim.x * gridDim.y + bl) * 4 + (threadIdx.x >> 6);
    if (t >= T) return;
    const int lane = threadIdx.x & 63;
    const float4* x4 = (const float4*)(x + (size_t)t * H);
    const float4* c4 = (const float4*)cw;
    const int h4n = H >> 2;
    float acc[NEXP];
#pragma unroll
    for (int e = 0; e < NEXP; ++e) acc[e] = 0.f;
    for (int h = lane; h < h4n; h += 64) {
      float4 xv = x4[h];
#pragma unroll
      for (int e = 0; e < NEXP; ++e) {
        float4 cv = c4[(size_t)e * h4n + h];
        acc[e] += xv.x * cv.x + xv.y * cv.y + xv.z * cv.z + xv.w * cv.w;
      }
    }
#pragma unroll
    for (int e = 0; e < NEXP; ++e) {
      float v = acc[e];
#pragma unroll
      for (int off = 32; off > 0; off >>= 1) v += __shfl_down(v, off, 64);
      acc[e] = v;
    }
    if (lane == 0) {
      float bids[NEXP];
#pragma unroll
      for (int e = 0; e < NEXP; ++e) {
        float lg = acc[e] + cb[e];
        float c = 1.f / (1.f + expf(-lg));
        bids[e] = c * wealth[e];
      }
      int i0 = 0;
      for (int e = 1; e < NEXP; ++e) if (bids[e] > bids[i0]) i0 = e;  // ties -> lower idx
      int i1 = (i0 == 0) ? 1 : 0;
      for (int e = 0; e < NEXP; ++e) if (e != i0 && bids[e] > bids[i1]) i1 = e;
      float ex = expf(bids[i1] - bids[i0]);
      float wsum = 1.f + ex;
      w_rt[2 * t]     = 1.f / wsum;
      w_rt[2 * t + 1] = ex / wsum;
      int p0 = atomicAdd(&counts[i0], 1);
      plist[i0 * T + p0] = 2 * t;
      int p1 = atomicAdd(&counts[i1], 1);
      plist[i1 * T + p1] = 2 * t + 1;
    }
  }
}

// counted-vmcnt gate: per-wave, allow only the N newest vmem ops to remain in
// flight (all older gll16 stages are complete in LDS), THEN barrier.
#define GATE(N) do {                                          \
    asm volatile("s_waitcnt vmcnt(" #N ")" ::: "memory");     \
    __builtin_amdgcn_s_barrier();                             \
    __builtin_amdgcn_sched_barrier(0);                        \
  } while (0)

// ---------------- gate+up GEMM: 4-buf counted-vmcnt pipeline, A in regs ----------------
// FIFO layout per phase k (order pinned by sched_barrier):
//   [stageB(k+3): 4 gll16][A(k+1): 4 loads]  -> GATE(8) leaves exactly these
//   8 newest in flight; everything older (incl. S(k+1)) is complete.
__global__ __launch_bounds__(256, 2) void gateup_kernel(
    const unsigned short* __restrict__ xb, const unsigned short* __restrict__ gwp,
    const unsigned short* __restrict__ uwp, const int* __restrict__ plist,
    const int* __restrict__ counts, unsigned short* __restrict__ act,
    int T, int H, int I) {
  const int nx = gridDim.x, ny = gridDim.y, nz = gridDim.z;
  int rt = blockIdx.x, it = blockIdx.y, e = blockIdx.z;
  {
    int nwg = nx * ny * nz;
    if (((nwg & 7) == 0) && (((nwg >> 3) % nx) == 0)) {
      int orig = blockIdx.x + nx * (blockIdx.y + ny * blockIdx.z);
      int idx = orig >> 3, xcd = orig & 7;
      int q = idx / nx;
      rt = idx - q * nx;
      int chunk = q * 8 + xcd;
      it = chunk % ny;
      e = chunk / ny;
    }
  }
  const int cnt = counts[e];
  const int row0 = rt * TILE;
  if (row0 >= cnt) return;
  const int nks = H / BK;  // 32

  __shared__ __align__(16) unsigned short Bg[4][TILE * BK];
  __shared__ __align__(16) unsigned short Bu[4][TILE * BK];

  const int tid = threadIdx.x, lane = tid & 63, wv = tid >> 6;
  const int wm = wv >> 1, wn = wv & 1;
  const int quad = lane >> 4, l15 = lane & 15;

  // A: per-lane register gather (4 rows/lane, 16B each)
  const unsigned short* ap[4];
#pragma unroll
  for (int mi = 0; mi < 4; ++mi) {
    int r = row0 + wm * 64 + mi * 16 + l15;
    if (r >= cnt) r = cnt - 1;
    ap[mi] = xb + (size_t)(plist[e * T + r] >> 1) * H + quad * 8;
  }

  const size_t pan = ((size_t)(e * ny + it) * nks) * (TILE * BK);
  const unsigned short* g0 = gwp + pan + (size_t)wv * 1024 + (size_t)lane * 8;
  const unsigned short* u0 = uwp + pan + (size_t)wv * 1024 + (size_t)lane * 8;

  float4v accg[4][4], accu[4][4];
#pragma unroll
  for (int a = 0; a < 4; ++a)
#pragma unroll
    for (int b = 0; b < 4; ++b) {
      float4v z = {0.f, 0.f, 0.f, 0.f};
      accg[a][b] = z; accu[a][b] = z;
    }

  auto stageB = [&](int kk, int b) {
    unsigned short* lG = &Bg[b][wv * 1024];
    unsigned short* lU = &Bu[b][wv * 1024];
    size_t kb = (size_t)kk * (TILE * BK);
    gll16(g0 + kb, lG); gll16(g0 + kb + 512, lG + 512);
    gll16(u0 + kb, lU); gll16(u0 + kb + 512, lU + 512);
  };

  short8 afA[4], afB[4];
#pragma unroll
  for (int mi = 0; mi < 4; ++mi) afA[mi] = *(const short8*)(ap[mi]);  // A(0)
  __builtin_amdgcn_sched_barrier(0);
  stageB(0, 0); stageB(1, 1); stageB(2, 2);
  __builtin_amdgcn_sched_barrier(0);
  GATE(8);  // newest 8 = {S1,S2} -> A(0),S(0) complete

  auto phase = [&](int k, short8 (&cur)[4], short8 (&nxt)[4]) {
    const int cb = k & 3;
    int ks_ = k + 3; if (ks_ >= nks) ks_ = nks - 1;     // tail clamp: uniform count
    stageB(ks_, (k + 3) & 3);                           // dead buffer when clamped
    __builtin_amdgcn_sched_barrier(0);
    int ka = k + 1; if (ka >= nks) ka = nks - 1;        // tail clamp: uniform count
#pragma unroll
    for (int mi = 0; mi < 4; ++mi)
      nxt[mi] = *(const short8*)(ap[mi] + (size_t)ka * BK);
    __builtin_amdgcn_sched_barrier(0);
    short8 bgf[4], buf_[4];
#pragma unroll
    for (int ni = 0; ni < 4; ++ni) {
      bgf[ni]  = *(const short8*)(&Bg[cb][(wn * 4 + ni) * 512 + quad * 128 + l15 * 8]);
      buf_[ni] = *(const short8*)(&Bu[cb][(wn * 4 + ni) * 512 + quad * 128 + l15 * 8]);
    }
#pragma unroll
    for (int mi = 0; mi < 4; ++mi)
#pragma unroll
      for (int ni = 0; ni < 4; ++ni) {
        accg[mi][ni] = __builtin_amdgcn_mfma_f32_16x16x32_bf16(cur[mi], bgf[ni], accg[mi][ni], 0, 0, 0);
        accu[mi][ni] = __builtin_amdgcn_mfma_f32_16x16x32_bf16(cur[mi], buf_[ni], accu[mi][ni], 0, 0, 0);
      }
    GATE(8);  // newest 8 = {S(k+3), A(k+1)} -> S(k+1) complete for next phase
  };
  for (int k = 0; k < nks; k += 2) { phase(k, afA, afB); phase(k + 1, afB, afA); }

  // epilogue: C/D layout col=lane&15, row=quad*4+reg
#pragma unroll
  for (int mi = 0; mi < 4; ++mi) {
    int rbase = wm * 64 + mi * 16 + quad * 4;
#pragma unroll
    for (int r = 0; r < 4; ++r) {
      int grow = row0 + rbase + r;
      if (grow < cnt) {
        int p = plist[e * T + grow];
        size_t base = (size_t)p * I + it * TILE + wn * 64 + l15;
#pragma unroll
        for (int ni = 0; ni < 4; ++ni) {
          float g = accg[mi][ni][r];
          float u = accu[mi][ni][r];
          float s = g / (1.f + __expf(-g)) * u;  // silu(g)*u
          act[base + ni * 16] = f2bf(s);
        }
      }
    }
  }
}

// ---------------- down GEMM: 4-buf counted-vmcnt pipeline, A in regs, split-K=2 ----------------
__global__ __launch_bounds__(256, 3) void down_kernel(
    const unsigned short* __restrict__ act, const unsigned short* __restrict__ dwp,
    const int* __restrict__ plist, const int* __restrict__ counts,
    float* __restrict__ part, int T, int H, int I) {
  const int nx = gridDim.x, ny = gridDim.y, nz = gridDim.z;
  int rt = blockIdx.x, ht = blockIdx.y, zz = blockIdx.z;
  {
    int nwg = nx * ny * nz;
    if (((nwg & 7) == 0) && (((nwg >> 3) % nx) == 0)) {
      int orig = blockIdx.x + nx * (blockIdx.y + ny * blockIdx.z);
      int idx = orig >> 3, xcd = orig & 7;
      int q = idx / nx;
      rt = idx - q * nx;
      int chunk = q * 8 + xcd;
      ht = chunk % ny;
      zz = chunk / ny;
    }
  }
  const int e = zz >> 1, split = zz & 1;
  const int cnt = counts[e];
  const int row0 = rt * TILE;
  if (row0 >= cnt) return;
  const int nks_tot = I / BK;      // 128
  const int nks = nks_tot >> 1;    // 64 per split
  const int k0 = split * nks;

  __shared__ __align__(16) unsigned short Bs[4][TILE * BK];

  const int tid = threadIdx.x, lane = tid & 63, wv = tid >> 6;
  const int wm = wv >> 1, wn = wv & 1;
  const int quad = lane >> 4, l15 = lane & 15;

  const unsigned short* ap[4];
#pragma unroll
  for (int mi = 0; mi < 4; ++mi) {
    int r = row0 + wm * 64 + mi * 16 + l15;
    if (r >= cnt) r = cnt - 1;
    ap[mi] = act + (size_t)plist[e * T + r] * I + k0 * BK + quad * 8;
  }

  const size_t pan = ((size_t)(e * ny + ht) * nks_tot + k0) * (TILE * BK);
  const unsigned short* b0 = dwp + pan + (size_t)wv * 1024 + (size_t)lane * 8;

  float4v acc[4][4];
#pragma unroll
  for (int a = 0; a < 4; ++a)
#pragma unroll
    for (int b = 0; b < 4; ++b) { float4v z = {0.f, 0.f, 0.f, 0.f}; acc[a][b] = z; }

  auto stageB = [&](int kk, int b) {
    unsigned short* lB = &Bs[b][wv * 1024];
    size_t kb = (size_t)kk * (TILE * BK);
    gll16(b0 + kb, lB);  gll16(b0 + kb + 512, lB + 512);
  };

  short8 afA[4], afB[4];
#pragma unroll
  for (int mi = 0; mi < 4; ++mi) afA[mi] = *(const short8*)(ap[mi]);  // A(0)
  __builtin_amdgcn_sched_barrier(0);
  stageB(0, 0); stageB(1, 1); stageB(2, 2);
  __builtin_amdgcn_sched_barrier(0);
  GATE(4);  // newest 4 = {S1,S2} -> A(0),S(0) complete

  auto phase = [&](int k, short8 (&cur)[4], short8 (&nxt)[4]) {
    const int cb = k & 3;
    int ks_ = k + 3; if (ks_ >= nks) ks_ = nks - 1;
    stageB(ks_, (k + 3) & 3);
    __builtin_amdgcn_sched_barrier(0);
    int ka = k + 1; if (ka >= nks) ka = nks - 1;
#pragma unroll
    for (int mi = 0; mi < 4; ++mi)
      nxt[mi] = *(const short8*)(ap[mi] + (size_t)ka * BK);
    __builtin_amdgcn_sched_barrier(0);
    short8 bf[4];
#pragma unroll
    for (int ni = 0; ni < 4; ++ni)
      bf[ni] = *(const short8*)(&Bs[cb][(wn * 4 + ni) * 512 + quad * 128 + l15 * 8]);
#pragma unroll
    for (int mi = 0; mi < 4; ++mi)
#pragma unroll
      for (int ni = 0; ni < 4; ++ni)
        acc[mi][ni] = __builtin_amdgcn_mfma_f32_16x16x32_bf16(cur[mi], bf[ni], acc[mi][ni], 0, 0, 0);
    GATE(6);  // newest 6 = {S(k+3) x2, A(k+1) x4} -> S(k+1) complete
  };
  for (int k = 0; k < nks; k += 2) { phase(k, afA, afB); phase(k + 1, afB, afA); }

#pragma unroll
  for (int mi = 0; mi < 4; ++mi) {
    int rbase = wm * 64 + mi * 16 + quad * 4;
#pragma unroll
    for (int r = 0; r < 4; ++r) {
      int grow = row0 + rbase + r;
      if (grow < cnt) {
        int p = plist[e * T + grow];
        size_t base = ((size_t)split * 2 * T + p) * H + ht * TILE + wn * 64 + l15;
#pragma unroll
        for (int ni = 0; ni < 4; ++ni)
          part[base + ni * 16] = acc[mi][ni][r];
      }
    }
  }
}

// ---------------- combine: out = w0*(p00+p10) + w1*(p01+p11) ----------------
__global__ __launch_bounds__(256) void combine_kernel(
    const float* __restrict__ part, const float* __restrict__ w_rt,
    float* __restrict__ out, int T, int H) {
  int h4 = H >> 2;
  int n4 = T * h4;
  int i = blockIdx.x * 256 + threadIdx.x;
  if (i >= n4) return;
  int t = i / h4;
  int c = i - t * h4;
  float w0 = w_rt[2 * t], w1 = w_rt[2 * t + 1];
  size_t splitoff = (size_t)2 * T * H / 4;  // in float4 units
  const float4* pa = (const float4*)(part + (size_t)(2 * t) * H);
  const float4* pb = (const float4*)(part + (size_t)(2 * t + 1) * H);
  float4 a0 = pa[c], a1 = pa[c + splitoff];
  float4 b0 = pb[c], b1 = pb[c + splitoff];
  float4 o;
  o.x = w0 * (a0.x + a1.x) + w1 * (b0.x + b1.x);
  o.y = w0 * (a0.y + a1.y) + w1 * (b0.y + b1.y);
  o.z = w0 * (a0.z + a1.z) + w1 * (b0.z + b1.z);
  o.w = w0 * (a0.w + a1.w) + w1 * (b0.w + b1.w);
  ((float4*)(out + (size_t)t * H))[c] = o;
}

extern "C" void kernel_launch(void* const* d_in, const int* in_sizes, int n_in,
                              void* d_out, int out_size, void* d_ws, size_t ws_size,
                              hipStream_t stream) {
  const float* x      = (const float*)d_in[0];
  const float* cw     = (const float*)d_in[1];
  const float* cb     = (const float*)d_in[2];
  const float* gw     = (const float*)d_in[3];
  const float* uw     = (const float*)d_in[4];
  const float* dw     = (const float*)d_in[5];
  const float* wealth = (const float*)d_in[6];
  float* out = (float*)d_out;

  const int H = in_sizes[1] / NEXP;          // conf_w (E,H)
  const int T = in_sizes[0] / H;             // hidden (B*S,H)
  const int I = in_sizes[3] / (NEXP * H);    // gate_w (E,I,H)

  char* ws = (char*)d_ws;
  size_t off = 0;
  unsigned short* xb  = (unsigned short*)(ws + off); off += (size_t)T * H * 2;
  unsigned short* act = (unsigned short*)(ws + off); off += (size_t)2 * T * I * 2;
  float* part = (float*)(ws + off); off += (size_t)2 * 2 * T * H * 4;  // split-K=2
  unsigned short* gwp = (unsigned short*)(ws + off); off += (size_t)NEXP * I * H * 2;
  unsigned short* uwp = (unsigned short*)(ws + off); off += (size_t)NEXP * I * H * 2;
  unsigned short* dwp = gwp;  // reuse: dw pack launched after gateup completes (same stream)
  int* plist = (int*)(ws + off); off += (size_t)NEXP * T * 4;
  float* w_rt = (float*)(ws + off); off += (size_t)T * 2 * 4;
  int* counts = (int*)(ws + off); off += NEXP * 4;

  hipMemsetAsync(counts, 0, NEXP * sizeof(int), stream);

  int n4 = (T * H) / 4;
  int bps = (H / BK) * (I / TILE);  // blocks per z-slice
  int nconv = (n4 + bps * 256 - 1) / (bps * 256);
  int nrout = ((T + 3) / 4 + bps - 1) / bps;
  int z_conv = 2 * NEXP, z_rout = z_conv + nconv;
  dim3 gprep(H / BK, I / TILE, z_rout + nrout);
  prep_kernel<<<gprep, 256, 0, stream>>>(gw, uw, x, cw, cb, wealth,
                                         gwp, uwp, xb, plist, counts, w_rt,
                                         T, H, n4, z_conv, z_rout);

  int ttiles = (T + TILE - 1) / TILE;
  dim3 g1(ttiles, I / TILE, NEXP);
  gateup_kernel<<<g1, 256, 0, stream>>>(xb, gwp, uwp, plist, counts, act, T, H, I);

  dim3 gpd(I / BK, H / TILE, NEXP);
  pack_w_kernel<<<gpd, 256, 0, stream>>>(dw, dwp, I);

  dim3 g2(ttiles, H / TILE, NEXP * 2);  // z = expert*2 + ksplit
  down_kernel<<<g2, 256, 0, stream>>>(act, dwp, plist, counts, part, T, H, I);

  combine_kernel<<<(n4 + 255) / 256, 256, 0, stream>>>(part, w_rt, out, T, H);
}

// Round 4
// 679.682 us; speedup vs baseline: 1.0318x; 1.0318x over previous
//
#include <hip/hip_runtime.h>
#include <math.h>

#define NEXP 8
#define TILE 128
#define BK 32

typedef __attribute__((ext_vector_type(8))) short short8;
typedef __attribute__((ext_vector_type(4))) float float4v;

__device__ __forceinline__ unsigned short f2bf(float f) {
  union { float f; unsigned u; } v; v.f = f;
  unsigned r = v.u + 0x7FFFu + ((v.u >> 16) & 1u);  // RNE
  return (unsigned short)(r >> 16);
}
__device__ __forceinline__ unsigned pack2(float a, float b) {
  return (unsigned)f2bf(a) | ((unsigned)f2bf(b) << 16);
}
// HW packed f32->bf16 (RNE), lo -> low half (T12 recipe, gfx950-verified)
__device__ __forceinline__ unsigned cvtpk(float lo, float hi) {
  unsigned r;
  asm("v_cvt_pk_bf16_f32 %0, %1, %2" : "=v"(r) : "v"(lo), "v"(hi));
  return r;
}
__device__ __forceinline__ uint4 cvt8(float4 a, float4 b) {
  uint4 o;
  o.x = cvtpk(a.x, a.y); o.y = cvtpk(a.z, a.w);
  o.z = cvtpk(b.x, b.y); o.w = cvtpk(b.z, b.w);
  return o;
}

// async global->LDS, 16B per lane. LDS dst is wave-uniform base + lane*16.
__device__ __forceinline__ void gll16(const void* g, void* l) {
  __builtin_amdgcn_global_load_lds(
      (const __attribute__((address_space(1))) unsigned int*)(unsigned long long)(uintptr_t)g,
      (__attribute__((address_space(3))) unsigned int*)(unsigned)(uintptr_t)l,
      16, 0, 0);
}

// ---------------- prep: x->bf16 + routing (weights are NOT packed anymore) ----------------
__global__ __launch_bounds__(256) void prep_kernel(
    const float* __restrict__ x, const float* __restrict__ cw,
    const float* __restrict__ cb, const float* __restrict__ wealth,
    unsigned short* __restrict__ xb, int* __restrict__ plist,
    int* __restrict__ counts, float* __restrict__ w_rt,
    int T, int H, int n4, int nconv) {
  const int b = blockIdx.x;
  if (b < nconv) {
    int i = b * 256 + threadIdx.x;
    if (i < n4) {
      float4 v = ((const float4*)x)[i];
      uint2 o; o.x = pack2(v.x, v.y); o.y = pack2(v.z, v.w);
      ((uint2*)xb)[i] = o;
    }
    return;
  }
  // routing: one wave per token (fp32, selection-exact)
  int t = (b - nconv) * 4 + (threadIdx.x >> 6);
  if (t >= T) return;
  const int lane = threadIdx.x & 63;
  const float4* x4 = (const float4*)(x + (size_t)t * H);
  const float4* c4 = (const float4*)cw;
  const int h4n = H >> 2;
  float acc[NEXP];
#pragma unroll
  for (int e = 0; e < NEXP; ++e) acc[e] = 0.f;
  for (int h = lane; h < h4n; h += 64) {
    float4 xv = x4[h];
#pragma unroll
    for (int e = 0; e < NEXP; ++e) {
      float4 cv = c4[(size_t)e * h4n + h];
      acc[e] += xv.x * cv.x + xv.y * cv.y + xv.z * cv.z + xv.w * cv.w;
    }
  }
#pragma unroll
  for (int e = 0; e < NEXP; ++e) {
    float v = acc[e];
#pragma unroll
    for (int off = 32; off > 0; off >>= 1) v += __shfl_down(v, off, 64);
    acc[e] = v;
  }
  if (lane == 0) {
    float bids[NEXP];
#pragma unroll
    for (int e = 0; e < NEXP; ++e) {
      float lg = acc[e] + cb[e];
      float c = 1.f / (1.f + expf(-lg));
      bids[e] = c * wealth[e];
    }
    int i0 = 0;
    for (int e = 1; e < NEXP; ++e) if (bids[e] > bids[i0]) i0 = e;  // ties -> lower idx
    int i1 = (i0 == 0) ? 1 : 0;
    for (int e = 0; e < NEXP; ++e) if (e != i0 && bids[e] > bids[i1]) i1 = e;
    float ex = expf(bids[i1] - bids[i0]);
    float wsum = 1.f + ex;
    w_rt[2 * t]     = 1.f / wsum;
    w_rt[2 * t + 1] = ex / wsum;
    int p0 = atomicAdd(&counts[i0], 1);
    plist[i0 * T + p0] = 2 * t;
    int p1 = atomicAdd(&counts[i1], 1);
    plist[i1 * T + p1] = 2 * t + 1;
  }
}

// ---------------- gate+up GEMM: round-1 2-phase dbuf, fused fp32->bf16 B staging ----------------
// A (gathered tokens, bf16) staged via global_load_lds; B (gw/uw fp32) reg-staged:
// float4 loads issued for tile k+1 at top of iter k (latency hides under MFMA),
// cvt_pk + ds_write into buf[cb^1] after MFMA, one __syncthreads per iter.
__global__ __launch_bounds__(256, 2) void gateup_kernel(
    const unsigned short* __restrict__ xb, const float* __restrict__ gw,
    const float* __restrict__ uw, const int* __restrict__ plist,
    const int* __restrict__ counts, unsigned short* __restrict__ act,
    int T, int H, int I) {
  const int nx = gridDim.x, ny = gridDim.y, nz = gridDim.z;
  // XCD-chunked remap: all row-tile blocks of one (e,it) panel on one XCD.
  int rt = blockIdx.x, it = blockIdx.y, e = blockIdx.z;
  {
    int nwg = nx * ny * nz;
    if (((nwg & 7) == 0) && (((nwg >> 3) % nx) == 0)) {
      int orig = blockIdx.x + nx * (blockIdx.y + ny * blockIdx.z);
      int idx = orig >> 3, xcd = orig & 7;
      int q = idx / nx;
      rt = idx - q * nx;
      int chunk = q * 8 + xcd;
      it = chunk % ny;
      e = chunk / ny;
    }
  }
  const int cnt = counts[e];
  const int row0 = rt * TILE;
  if (row0 >= cnt) return;
  const int nks = H / BK;  // 32

  __shared__ __align__(16) unsigned short As[2][TILE * BK];
  __shared__ __align__(16) unsigned short Bg[2][TILE * BK];
  __shared__ __align__(16) unsigned short Bu[2][TILE * BK];

  const int tid = threadIdx.x, lane = tid & 63, wv = tid >> 6;
  const int wm = wv >> 1, wn = wv & 1;
  const int quad = lane >> 4, l15 = lane & 15;

  // A gather (fragment-major): lane stages row (lane&15), colgrp (lane>>4)
  int ri0 = row0 + wv * 32 + l15;
  int ri1 = ri0 + 16;
  if (ri0 >= cnt) ri0 = cnt - 1;
  if (ri1 >= cnt) ri1 = cnt - 1;
  const unsigned short* a0 = xb + (size_t)(plist[e * T + ri0] >> 1) * H + quad * 8;
  const unsigned short* a1 = xb + (size_t)(plist[e * T + ri1] >> 1) * H + quad * 8;

  // B fp32 direct: wave wv covers rows [wv*32, wv*32+32); 2 lanes per row.
  const int brow = wv * 32 + (lane >> 1);
  const int bhalf = lane & 1;  // 16 cols each
  const float* gsrc = gw + ((size_t)e * I + (size_t)it * TILE + brow) * H + bhalf * 16;
  const float* usrc = uw + ((size_t)e * I + (size_t)it * TILE + brow) * H + bhalf * 16;
  // fragment-major LDS offset: [chunk brow>>4][colgrp 2*bhalf(+1)][row brow&15][8]
  const int woff = (brow >> 4) * 512 + bhalf * 256 + (brow & 15) * 8;

  float4v accg[4][4], accu[4][4];
#pragma unroll
  for (int a = 0; a < 4; ++a)
#pragma unroll
    for (int b = 0; b < 4; ++b) {
      float4v z = {0.f, 0.f, 0.f, 0.f};
      accg[a][b] = z; accu[a][b] = z;
    }

  float4 gr0, gr1, gr2, gr3, ur0, ur1, ur2, ur3;  // named: no runtime indexing (rule #20)
  auto loadB = [&](int kk) {
    const float4* gs = (const float4*)(gsrc + (size_t)kk * BK);
    const float4* us = (const float4*)(usrc + (size_t)kk * BK);
    gr0 = gs[0]; gr1 = gs[1]; gr2 = gs[2]; gr3 = gs[3];
    ur0 = us[0]; ur1 = us[1]; ur2 = us[2]; ur3 = us[3];
  };
  auto writeB = [&](int b) {
    uint4 q0 = cvt8(gr0, gr1), q1 = cvt8(gr2, gr3);
    uint4 q2 = cvt8(ur0, ur1), q3 = cvt8(ur2, ur3);
    *(uint4*)(&Bg[b][woff])       = q0;
    *(uint4*)(&Bg[b][woff + 128]) = q1;
    *(uint4*)(&Bu[b][woff])       = q2;
    *(uint4*)(&Bu[b][woff + 128]) = q3;
  };
  auto stageA = [&](int kk, int b) {
    gll16(a0 + (size_t)kk * BK, &As[b][wv * 1024]);
    gll16(a1 + (size_t)kk * BK, &As[b][wv * 1024 + 512]);
  };

  loadB(0);
  stageA(0, 0);
  writeB(0);
  __syncthreads();

  for (int k = 0; k < nks; ++k) {
    const int cb = k & 1;
    if (k + 1 < nks) { loadB(k + 1); stageA(k + 1, cb ^ 1); }
    short8 af[4], bgf[4], buf_[4];
#pragma unroll
    for (int mi = 0; mi < 4; ++mi)
      af[mi] = *(const short8*)(&As[cb][(wm * 4 + mi) * 512 + quad * 128 + l15 * 8]);
#pragma unroll
    for (int ni = 0; ni < 4; ++ni) {
      bgf[ni]  = *(const short8*)(&Bg[cb][(wn * 4 + ni) * 512 + quad * 128 + l15 * 8]);
      buf_[ni] = *(const short8*)(&Bu[cb][(wn * 4 + ni) * 512 + quad * 128 + l15 * 8]);
    }
#pragma unroll
    for (int mi = 0; mi < 4; ++mi)
#pragma unroll
      for (int ni = 0; ni < 4; ++ni) {
        accg[mi][ni] = __builtin_amdgcn_mfma_f32_16x16x32_bf16(af[mi], bgf[ni], accg[mi][ni], 0, 0, 0);
        accu[mi][ni] = __builtin_amdgcn_mfma_f32_16x16x32_bf16(af[mi], buf_[ni], accu[mi][ni], 0, 0, 0);
      }
    if (k + 1 < nks) writeB(cb ^ 1);  // writes other buffer: race-free pre-barrier
    __syncthreads();
  }

  // epilogue: C/D layout col=lane&15, row=quad*4+reg
#pragma unroll
  for (int mi = 0; mi < 4; ++mi) {
    int rbase = wm * 64 + mi * 16 + quad * 4;
#pragma unroll
    for (int r = 0; r < 4; ++r) {
      int grow = row0 + rbase + r;
      if (grow < cnt) {
        int p = plist[e * T + grow];
        size_t base = (size_t)p * I + it * TILE + wn * 64 + l15;
#pragma unroll
        for (int ni = 0; ni < 4; ++ni) {
          float g = accg[mi][ni][r];
          float u = accu[mi][ni][r];
          float s = g / (1.f + __expf(-g)) * u;  // silu(g)*u
          act[base + ni * 16] = f2bf(s);
        }
      }
    }
  }
}

// ---------------- down GEMM: 2-phase dbuf, fused fp32->bf16 B staging, split-K=2 ----------------
__global__ __launch_bounds__(256, 3) void down_kernel(
    const unsigned short* __restrict__ act, const float* __restrict__ dw,
    const int* __restrict__ plist, const int* __restrict__ counts,
    float* __restrict__ part, int T, int H, int I) {
  const int nx = gridDim.x, ny = gridDim.y, nz = gridDim.z;
  int rt = blockIdx.x, ht = blockIdx.y, zz = blockIdx.z;
  {
    int nwg = nx * ny * nz;
    if (((nwg & 7) == 0) && (((nwg >> 3) % nx) == 0)) {
      int orig = blockIdx.x + nx * (blockIdx.y + ny * blockIdx.z);
      int idx = orig >> 3, xcd = orig & 7;
      int q = idx / nx;
      rt = idx - q * nx;
      int chunk = q * 8 + xcd;
      ht = chunk % ny;
      zz = chunk / ny;
    }
  }
  const int e = zz >> 1, split = zz & 1;
  const int cnt = counts[e];
  const int row0 = rt * TILE;
  if (row0 >= cnt) return;
  const int nks_tot = I / BK;      // 128
  const int nks = nks_tot >> 1;    // 64 per split
  const int k0 = split * nks;

  __shared__ __align__(16) unsigned short As[2][TILE * BK];
  __shared__ __align__(16) unsigned short Bs[2][TILE * BK];

  const int tid = threadIdx.x, lane = tid & 63, wv = tid >> 6;
  const int wm = wv >> 1, wn = wv & 1;
  const int quad = lane >> 4, l15 = lane & 15;

  int ri0 = row0 + wv * 32 + l15;
  int ri1 = ri0 + 16;
  if (ri0 >= cnt) ri0 = cnt - 1;
  if (ri1 >= cnt) ri1 = cnt - 1;
  const unsigned short* a0 = act + (size_t)plist[e * T + ri0] * I + k0 * BK + quad * 8;
  const unsigned short* a1 = act + (size_t)plist[e * T + ri1] * I + k0 * BK + quad * 8;

  const int brow = wv * 32 + (lane >> 1);
  const int bhalf = lane & 1;
  const float* dsrc = dw + ((size_t)e * H + (size_t)ht * TILE + brow) * I + k0 * BK + bhalf * 16;
  const int woff = (brow >> 4) * 512 + bhalf * 256 + (brow & 15) * 8;

  float4v acc[4][4];
#pragma unroll
  for (int a = 0; a < 4; ++a)
#pragma unroll
    for (int b = 0; b < 4; ++b) { float4v z = {0.f, 0.f, 0.f, 0.f}; acc[a][b] = z; }

  float4 dr0, dr1, dr2, dr3;
  auto loadB = [&](int kk) {
    const float4* ds = (const float4*)(dsrc + (size_t)kk * BK);
    dr0 = ds[0]; dr1 = ds[1]; dr2 = ds[2]; dr3 = ds[3];
  };
  auto writeB = [&](int b) {
    uint4 q0 = cvt8(dr0, dr1), q1 = cvt8(dr2, dr3);
    *(uint4*)(&Bs[b][woff])       = q0;
    *(uint4*)(&Bs[b][woff + 128]) = q1;
  };
  auto stageA = [&](int kk, int b) {
    gll16(a0 + (size_t)kk * BK, &As[b][wv * 1024]);
    gll16(a1 + (size_t)kk * BK, &As[b][wv * 1024 + 512]);
  };

  loadB(0);
  stageA(0, 0);
  writeB(0);
  __syncthreads();

  for (int k = 0; k < nks; ++k) {
    const int cb = k & 1;
    if (k + 1 < nks) { loadB(k + 1); stageA(k + 1, cb ^ 1); }
    short8 af[4], bf[4];
#pragma unroll
    for (int mi = 0; mi < 4; ++mi)
      af[mi] = *(const short8*)(&As[cb][(wm * 4 + mi) * 512 + quad * 128 + l15 * 8]);
#pragma unroll
    for (int ni = 0; ni < 4; ++ni)
      bf[ni] = *(const short8*)(&Bs[cb][(wn * 4 + ni) * 512 + quad * 128 + l15 * 8]);
#pragma unroll
    for (int mi = 0; mi < 4; ++mi)
#pragma unroll
      for (int ni = 0; ni < 4; ++ni)
        acc[mi][ni] = __builtin_amdgcn_mfma_f32_16x16x32_bf16(af[mi], bf[ni], acc[mi][ni], 0, 0, 0);
    if (k + 1 < nks) writeB(cb ^ 1);
    __syncthreads();
  }

#pragma unroll
  for (int mi = 0; mi < 4; ++mi) {
    int rbase = wm * 64 + mi * 16 + quad * 4;
#pragma unroll
    for (int r = 0; r < 4; ++r) {
      int grow = row0 + rbase + r;
      if (grow < cnt) {
        int p = plist[e * T + grow];
        size_t base = ((size_t)split * 2 * T + p) * H + ht * TILE + wn * 64 + l15;
#pragma unroll
        for (int ni = 0; ni < 4; ++ni)
          part[base + ni * 16] = acc[mi][ni][r];
      }
    }
  }
}

// ---------------- combine: out = w0*(p00+p10) + w1*(p01+p11) ----------------
__global__ __launch_bounds__(256) void combine_kernel(
    const float* __restrict__ part, const float* __restrict__ w_rt,
    float* __restrict__ out, int T, int H) {
  int h4 = H >> 2;
  int n4 = T * h4;
  int i = blockIdx.x * 256 + threadIdx.x;
  if (i >= n4) return;
  int t = i / h4;
  int c = i - t * h4;
  float w0 = w_rt[2 * t], w1 = w_rt[2 * t + 1];
  size_t splitoff = (size_t)2 * T * H / 4;  // in float4 units
  const float4* pa = (const float4*)(part + (size_t)(2 * t) * H);
  const float4* pb = (const float4*)(part + (size_t)(2 * t + 1) * H);
  float4 a0 = pa[c], a1 = pa[c + splitoff];
  float4 b0 = pb[c], b1 = pb[c + splitoff];
  float4 o;
  o.x = w0 * (a0.x + a1.x) + w1 * (b0.x + b1.x);
  o.y = w0 * (a0.y + a1.y) + w1 * (b0.y + b1.y);
  o.z = w0 * (a0.z + a1.z) + w1 * (b0.z + b1.z);
  o.w = w0 * (a0.w + a1.w) + w1 * (b0.w + b1.w);
  ((float4*)(out + (size_t)t * H))[c] = o;
}

extern "C" void kernel_launch(void* const* d_in, const int* in_sizes, int n_in,
                              void* d_out, int out_size, void* d_ws, size_t ws_size,
                              hipStream_t stream) {
  const float* x      = (const float*)d_in[0];
  const float* cw     = (const float*)d_in[1];
  const float* cb     = (const float*)d_in[2];
  const float* gw     = (const float*)d_in[3];
  const float* uw     = (const float*)d_in[4];
  const float* dw     = (const float*)d_in[5];
  const float* wealth = (const float*)d_in[6];
  float* out = (float*)d_out;

  const int H = in_sizes[1] / NEXP;          // conf_w (E,H)
  const int T = in_sizes[0] / H;             // hidden (B*S,H)
  const int I = in_sizes[3] / (NEXP * H);    // gate_w (E,I,H)

  char* ws = (char*)d_ws;
  size_t off = 0;
  unsigned short* xb  = (unsigned short*)(ws + off); off += (size_t)T * H * 2;
  unsigned short* act = (unsigned short*)(ws + off); off += (size_t)2 * T * I * 2;
  float* part = (float*)(ws + off); off += (size_t)2 * 2 * T * H * 4;  // split-K=2
  int* plist = (int*)(ws + off); off += (size_t)NEXP * T * 4;
  float* w_rt = (float*)(ws + off); off += (size_t)T * 2 * 4;
  int* counts = (int*)(ws + off); off += NEXP * 4;

  hipMemsetAsync(counts, 0, NEXP * sizeof(int), stream);

  int n4 = (T * H) / 4;
  int nconv = (n4 + 255) / 256;
  int nrout = (T + 3) / 4;
  prep_kernel<<<nconv + nrout, 256, 0, stream>>>(x, cw, cb, wealth, xb, plist,
                                                 counts, w_rt, T, H, n4, nconv);

  int ttiles = (T + TILE - 1) / TILE;
  dim3 g1(ttiles, I / TILE, NEXP);
  gateup_kernel<<<g1, 256, 0, stream>>>(xb, gw, uw, plist, counts, act, T, H, I);

  dim3 g2(ttiles, H / TILE, NEXP * 2);  // z = expert*2 + ksplit
  down_kernel<<<g2, 256, 0, stream>>>(act, dw, plist, counts, part, T, H, I);

  combine_kernel<<<(n4 + 255) / 256, 256, 0, stream>>>(part, w_rt, out, T, H);
}